// Round 7
// baseline (157.969 us; speedup 1.0000x reference)
//
#include <hip/hip_runtime.h>
#include <cstdint>

// ---------------------------------------------------------------------------
// FP8 QDQ Conv2d:  out = conv2d(qdq_fp8(x,2), w*2, pad=1) + bias
//                = 4 * conv2d(fp8(x/2), fp8(w)) + bias     (exact in fp8)
// x: (32,128,56,56) f32 NCHW; w: (256,128,3,3) f32 (fp8-representable); b: (256,)
// out: (32,256,56,56) f32.  Implicit GEMM: M = 100352, N = 256, K = 9*128.
//
// R7 = R1's geometry (128x128 tile, 256 thr, 2x2 waves, BK=128/rs, 16x16x32
// fp8 MFMA) with A moved OUT of LDS: A-fragments read directly global->VGPR
// (L2-hot, 16 consecutive pixel-rows per frag, halo via zero-page base
// select). LDS holds only B (16KB/step, double-buffered = 32KB), staged with
// prefetch-before-compute. Halves per-step LDS traffic (the R1 bottleneck:
// 96KB/step = 768cyc LDS vs 314cyc MFMA -> 40% MfmaUtil ceiling, measured 33%).
// ---------------------------------------------------------------------------

#define NB   32
#define CIN  128
#define HW   56
#define KOUT 256
#define MTOT (32 * 56 * 56)                      // 100352

#define ACT_BYTES (32u * 56u * 56u * 128u)       // 12,845,056  NHWC fp8
#define WT_OFF    ACT_BYTES
#define WT_BYTES  (9u * 256u * 128u)             // 294,912     [rs][k][c] fp8
#define ZP_OFF    (WT_OFF + WT_BYTES)            // 128B zero page for halo rows

typedef float        f32x4 __attribute__((ext_vector_type(4)));
typedef unsigned int u32x4 __attribute__((ext_vector_type(4)));

// --------------------------- fp8 pack helpers ------------------------------
__device__ __forceinline__ unsigned int pack2_fp8(float a, float b) {
  a = fminf(fmaxf(a, -448.f), 448.f);
  b = fminf(fmaxf(b, -448.f), 448.f);
  // v_cvt_pk_fp8_f32: RNE, saturating, OCP e4m3fn on gfx950. byte0=a, byte1=b.
  return (unsigned int)__builtin_amdgcn_cvt_pk_fp8_f32(a, b, 0, false);
}

// ------------------- kernel 1: qdq + NCHW -> NHWC fp8 ----------------------
__global__ __launch_bounds__(256) void qdq_pack(const float* __restrict__ X,
                                                unsigned char* __restrict__ act) {
  const int nh = blockIdx.x;               // 0..1791
  const int n = nh / HW, h = nh - n * HW;
  const float* xb = X + (size_t)n * (CIN * HW * HW) + h * HW;  // + c*3136 + w
  unsigned char* ob = act + (size_t)nh * (HW * CIN);

  for (int i = 0; i < 2; ++i) {
    int item = threadIdx.x + i * 256;
    if (item >= HW * 8) break;             // 56 w * 8 c-groups of 16
    int w = item % HW, cg = item / HW;
    unsigned int dw[4];
#pragma unroll
    for (int jj = 0; jj < 4; ++jj) {
      int c0 = cg * 16 + jj * 4;
      float v0 = xb[(c0 + 0) * 3136 + w] * 0.5f;
      float v1 = xb[(c0 + 1) * 3136 + w] * 0.5f;
      float v2 = xb[(c0 + 2) * 3136 + w] * 0.5f;
      float v3 = xb[(c0 + 3) * 3136 + w] * 0.5f;
      unsigned int lo = pack2_fp8(v0, v1) & 0xffffu;
      unsigned int hi = pack2_fp8(v2, v3) & 0xffffu;
      dw[jj] = lo | (hi << 16);
    }
    u32x4 v = {dw[0], dw[1], dw[2], dw[3]};
    *(u32x4*)(ob + w * CIN + cg * 16) = v;
  }
}

// --------------- kernel 2: weight OIHW f32 -> [rs][k][c] fp8 ---------------
__global__ __launch_bounds__(256) void pack_weight(const float* __restrict__ W,
                                                   unsigned char* __restrict__ wt,
                                                   unsigned int* __restrict__ zp) {
  if (blockIdx.x == 0 && threadIdx.x < 32) zp[threadIdx.x] = 0u;
  int gid = blockIdx.x * 256 + threadIdx.x;   // one dword (4 c) per thread
  int o = gid * 4;
  if (o >= (int)WT_BYTES) return;
  int rs = o >> 15;                // /32768 (= 256*128)
  int rem = o & 32767;
  int k  = rem >> 7;
  int c0 = rem & 127;
  // W[k][c][r][s] at k*1152 + c*9 + rs
  float v0 = W[k * 1152 + (c0 + 0) * 9 + rs];
  float v1 = W[k * 1152 + (c0 + 1) * 9 + rs];
  float v2 = W[k * 1152 + (c0 + 2) * 9 + rs];
  float v3 = W[k * 1152 + (c0 + 3) * 9 + rs];
  unsigned int dw = (pack2_fp8(v0, v1) & 0xffffu) | (pack2_fp8(v2, v3) << 16);
  *(unsigned int*)(wt + o) = dw;
}

// ------------------------- kernel 3: implicit GEMM -------------------------
__device__ __forceinline__ void g2l16(const void* g, void* l) {
  __builtin_amdgcn_global_load_lds((const __attribute__((address_space(1))) void*)g,
                                   (__attribute__((address_space(3))) void*)l,
                                   16, 0, 0);
}

__global__ __launch_bounds__(256) void conv_mfma(const unsigned char* __restrict__ act,
                                                 const unsigned char* __restrict__ wt,
                                                 const unsigned char* __restrict__ zp,
                                                 const float* __restrict__ bias,
                                                 float* __restrict__ out) {
  __shared__ __align__(16) unsigned char ldsB[2][16384];   // [128 k][128 c] x2
  const int tid  = threadIdx.x;
  const int lane = tid & 63;
  const int wid  = tid >> 6;
  const int wr   = wid >> 1, wc = wid & 1;            // 2x2 waves -> 64x64 each
  const int bm   = blockIdx.x << 7;                   // 784 m-tiles
  const int bn   = blockIdx.y << 7;                   // 2 k-tiles

  // B staging geometry (identical to R1): 8 thr x 16B per 128B row, 4 rounds
  const int srow   = tid >> 3;                        // 0..31
  const int sphys  = (tid & 7) << 4;                  // linear LDS dest chunk
  const int schunk = ((tid & 7) ^ (srow & 7)) << 4;   // XOR-swizzled global src

  // per-fragment-row pixel coords (lane-resident)
  int fn[4], fh[4], fw[4];
#pragma unroll
  for (int mi = 0; mi < 4; ++mi) {
    int m = bm + (wr << 6) + (mi << 4) + (lane & 15);
    int n = m / 3136;
    int hw = m - n * 3136;
    int h = hw / 56;
    fn[mi] = n; fh[mi] = h; fw[mi] = hw - h * 56;
  }
  const int laneoff = (lane >> 4) << 3;               // 8 K-bytes per lane-group

  auto stageB = [&](unsigned char* buf, int rs) {
    const unsigned char* wseg = wt + rs * (KOUT * CIN);
#pragma unroll
    for (int q = 0; q < 4; ++q) {
      int kl = srow + 32 * q;
      g2l16(wseg + ((bn + kl) << 7) + schunk, buf + (kl << 7) + sphys);
    }
  };
  // A-fragment base pointers for one rs (zero-page when padded out)
  auto abase = [&](int mi, int r, int s) -> const unsigned char* {
    int hi = fh[mi] + r - 1;
    int wi = fw[mi] + s - 1;
    bool ok = ((unsigned)hi < 56u) && ((unsigned)wi < 56u);
    return (ok ? act + ((size_t)((fn[mi] * 56 + hi) * 56 + wi) << 7) : zp) + laneoff;
  };

  const f32x4 zero = {0.f, 0.f, 0.f, 0.f};
  f32x4 acc[4][4];
#pragma unroll
  for (int i = 0; i < 4; ++i)
#pragma unroll
    for (int j = 0; j < 4; ++j) acc[i][j] = zero;

  stageB(ldsB[0], 0);
  // depth-1 A prefetch: kk=0 frags of rs=0
  long av0[4];
#pragma unroll
  for (int mi = 0; mi < 4; ++mi) av0[mi] = *(const long*)(abase(mi, 0, 0));
  __syncthreads();

#pragma unroll
  for (int rs = 0; rs < 9; ++rs) {
    const int r = rs / 3, s = rs - 3 * r;
    if (rs < 8) stageB(ldsB[(rs + 1) & 1], rs + 1);   // lands behind end barrier

    // B fragments from LDS (read once per wave per step)
    const unsigned char* bbuf = ldsB[rs & 1];
    long bv[4][4];
#pragma unroll
    for (int kk = 0; kk < 4; ++kk)
#pragma unroll
      for (int ni = 0; ni < 4; ++ni) {
        int col = (wc << 6) + (ni << 4) + (lane & 15);
        bv[kk][ni] = *(const long*)(
            bbuf + (col << 7) + (((kk << 5) + laneoff) ^ ((col & 7) << 4)));
      }

    // A fragments straight from global (L2-hot); kk=0 already prefetched
    const unsigned char* ab[4];
#pragma unroll
    for (int mi = 0; mi < 4; ++mi) ab[mi] = abase(mi, r, s);
    long av[4][4];
#pragma unroll
    for (int mi = 0; mi < 4; ++mi) av[0][mi] = av0[mi];
#pragma unroll
    for (int kk = 1; kk < 4; ++kk)
#pragma unroll
      for (int mi = 0; mi < 4; ++mi)
        av[kk][mi] = *(const long*)(ab[mi] + (kk << 5));

    // prefetch kk=0 of NEXT rs before the MFMA block (hidden under compute)
    if (rs < 8) {
      const int rn = (rs + 1) / 3, sn = (rs + 1) - 3 * ((rs + 1) / 3);
#pragma unroll
      for (int mi = 0; mi < 4; ++mi) av0[mi] = *(const long*)(abase(mi, rn, sn));
    }

#pragma unroll
    for (int kk = 0; kk < 4; ++kk)
#pragma unroll
      for (int mi = 0; mi < 4; ++mi)
#pragma unroll
        for (int ni = 0; ni < 4; ++ni)
          acc[mi][ni] = __builtin_amdgcn_mfma_f32_16x16x32_fp8_fp8(
              av[kk][mi], bv[kk][ni], acc[mi][ni], 0, 0, 0);

    __syncthreads();   // drains stage(rs+1); separates bbuf reuse at rs+2
  }

  // epilogue: out[n][k][hw] = 4*acc + bias[k]; 4 consecutive m per lane = float4
#pragma unroll
  for (int ni = 0; ni < 4; ++ni) {
    int k = bn + (wc << 6) + (ni << 4) + (lane & 15);
    float bvv = bias[k];
#pragma unroll
    for (int mi = 0; mi < 4; ++mi) {
      int m = bm + (wr << 6) + (mi << 4) + ((lane >> 4) << 2);
      int n = m / 3136;
      int hw = m - n * 3136;
      f32x4 v = acc[mi][ni];
      v = v * 4.0f + bvv;
      *(f32x4*)(out + (size_t)(n * KOUT + k) * 3136 + hw) = v;
    }
  }
}

// ---------------------------------------------------------------------------
extern "C" void kernel_launch(void* const* d_in, const int* in_sizes, int n_in,
                              void* d_out, int out_size, void* d_ws, size_t ws_size,
                              hipStream_t stream) {
  const float* X = (const float*)d_in[0];
  const float* W = (const float*)d_in[1];
  const float* B = (const float*)d_in[2];
  float* out = (float*)d_out;

  unsigned char* act = (unsigned char*)d_ws;
  unsigned char* wtb = act + WT_OFF;
  unsigned char* zp  = act + ZP_OFF;

  hipLaunchKernelGGL(qdq_pack,    dim3(NB * HW), dim3(256), 0, stream, X, act);
  hipLaunchKernelGGL(pack_weight, dim3(288),     dim3(256), 0, stream, W, wtb,
                     (unsigned int*)zp);
  hipLaunchKernelGGL(conv_mfma,   dim3(784, 2),  dim3(256), 0, stream, act, wtb, zp, B,
                     out);
}

// Round 8
// 108.156 us; speedup vs baseline: 1.4606x; 1.4606x over previous
//
#include <hip/hip_runtime.h>
#include <cstdint>

// ---------------------------------------------------------------------------
// FP8 QDQ Conv2d:  out = conv2d(qdq_fp8(x,2), w*2, pad=1) + bias
//                = 4 * conv2d(fp8(x/2), fp8(w)) + bias     (exact in fp8)
// x: (32,128,56,56) f32 NCHW; w: (256,128,3,3) f32 (fp8-representable); b: (256,)
// out: (32,256,56,56) f32.  Implicit GEMM: M = 100352, N = 256, K = 9*128.
//
// R8: 8-phase-style schedule (m201/T3 port). BM=256 x BN=128, 512 thr
// (8 waves, 4x2; per-wave 64x64 = R1 economics). R1's exact LDS layout,
// swizzle and read addressing. A+B double-buffered (96KB, 1 block/CU).
// Per rs: 4 phases {8 ds_read_b64 || 2 g2l16 stage(rs+1) -> barrier ->
// lgkmcnt(0) -> setprio MFMA x16 -> barrier}; ONE vmcnt(0) per rs after
// phase 3 (loads issued 4 phases earlier, L2-hot -> drain ~free).
// ---------------------------------------------------------------------------

#define NB   32
#define CIN  128
#define HW   56
#define KOUT 256
#define MTOT (32 * 56 * 56)                      // 100352

#define ACT_BYTES (32u * 56u * 56u * 128u)       // 12,845,056  NHWC fp8
#define WT_OFF    ACT_BYTES
#define WT_BYTES  (9u * 256u * 128u)             // 294,912     [rs][k][c] fp8
#define ZP_OFF    (WT_OFF + WT_BYTES)            // 128B zero page for halo rows

typedef float        f32x4 __attribute__((ext_vector_type(4)));
typedef unsigned int u32x4 __attribute__((ext_vector_type(4)));

// --------------------------- fp8 pack helpers ------------------------------
__device__ __forceinline__ unsigned int pack2_fp8(float a, float b) {
  a = fminf(fmaxf(a, -448.f), 448.f);
  b = fminf(fmaxf(b, -448.f), 448.f);
  // v_cvt_pk_fp8_f32: RNE, saturating, OCP e4m3fn on gfx950. byte0=a, byte1=b.
  return (unsigned int)__builtin_amdgcn_cvt_pk_fp8_f32(a, b, 0, false);
}

// ------------------- kernel 1: qdq + NCHW -> NHWC fp8 ----------------------
__global__ __launch_bounds__(256) void qdq_pack(const float* __restrict__ X,
                                                unsigned char* __restrict__ act) {
  const int nh = blockIdx.x;               // 0..1791
  const int n = nh / HW, h = nh - n * HW;
  const float* xb = X + (size_t)n * (CIN * HW * HW) + h * HW;  // + c*3136 + w
  unsigned char* ob = act + (size_t)nh * (HW * CIN);

  for (int i = 0; i < 2; ++i) {
    int item = threadIdx.x + i * 256;
    if (item >= HW * 8) break;             // 56 w * 8 c-groups of 16
    int w = item % HW, cg = item / HW;
    unsigned int dw[4];
#pragma unroll
    for (int jj = 0; jj < 4; ++jj) {
      int c0 = cg * 16 + jj * 4;
      float v0 = xb[(c0 + 0) * 3136 + w] * 0.5f;
      float v1 = xb[(c0 + 1) * 3136 + w] * 0.5f;
      float v2 = xb[(c0 + 2) * 3136 + w] * 0.5f;
      float v3 = xb[(c0 + 3) * 3136 + w] * 0.5f;
      unsigned int lo = pack2_fp8(v0, v1) & 0xffffu;
      unsigned int hi = pack2_fp8(v2, v3) & 0xffffu;
      dw[jj] = lo | (hi << 16);
    }
    u32x4 v = {dw[0], dw[1], dw[2], dw[3]};
    *(u32x4*)(ob + w * CIN + cg * 16) = v;
  }
}

// --------------- kernel 2: weight OIHW f32 -> [rs][k][c] fp8 ---------------
__global__ __launch_bounds__(256) void pack_weight(const float* __restrict__ W,
                                                   unsigned char* __restrict__ wt,
                                                   unsigned int* __restrict__ zp) {
  if (blockIdx.x == 0 && threadIdx.x < 32) zp[threadIdx.x] = 0u;
  int gid = blockIdx.x * 256 + threadIdx.x;   // one dword (4 c) per thread
  int o = gid * 4;
  if (o >= (int)WT_BYTES) return;
  int rs = o >> 15;                // /32768 (= 256*128)
  int rem = o & 32767;
  int k  = rem >> 7;
  int c0 = rem & 127;
  // W[k][c][r][s] at k*1152 + c*9 + rs
  float v0 = W[k * 1152 + (c0 + 0) * 9 + rs];
  float v1 = W[k * 1152 + (c0 + 1) * 9 + rs];
  float v2 = W[k * 1152 + (c0 + 2) * 9 + rs];
  float v3 = W[k * 1152 + (c0 + 3) * 9 + rs];
  unsigned int dw = (pack2_fp8(v0, v1) & 0xffffu) | (pack2_fp8(v2, v3) << 16);
  *(unsigned int*)(wt + o) = dw;
}

// ------------------------- kernel 3: implicit GEMM -------------------------
__device__ __forceinline__ void g2l16(const void* g, void* l) {
  __builtin_amdgcn_global_load_lds((const __attribute__((address_space(1))) void*)g,
                                   (__attribute__((address_space(3))) void*)l,
                                   16, 0, 0);
}

__global__ __launch_bounds__(512) void conv_mfma(const unsigned char* __restrict__ act,
                                                 const unsigned char* __restrict__ wt,
                                                 const unsigned char* __restrict__ zp,
                                                 const float* __restrict__ bias,
                                                 float* __restrict__ out) {
  __shared__ __align__(16) unsigned char ldsA[2][32768];   // [256 m][128 c] x2
  __shared__ __align__(16) unsigned char ldsB[2][16384];   // [128 k][128 c] x2
  const int tid  = threadIdx.x;
  const int lane = tid & 63;
  const int wid  = tid >> 6;                   // 0..7
  const int wr   = wid >> 1, wc = wid & 1;     // 4x2 waves -> 64x64 out each

  // XCD-aware bijective swizzle over 392 m-tiles (392 = 8*49)
  const int bx  = (int)blockIdx.x;
  const int bmi = (bx & 7) * 49 + (bx >> 3);
  const int bm  = bmi << 8;                    // 256-row m-tile
  const int bn  = (int)blockIdx.y << 7;        // 2 k-tiles

  // staging geometry: 8 threads x 16B per 128B row; 64 rows/round
  const int srow   = tid >> 3;                        // 0..63
  const int sphys  = (tid & 7) << 4;                  // linear LDS dest chunk
  const int schunk = ((tid & 7) ^ (srow & 7)) << 4;   // XOR-swizzled global src

  int an_[4], ah_[4], aw_[4];
#pragma unroll
  for (int q = 0; q < 4; ++q) {
    int m = bm + srow + 64 * q;
    int n = m / 3136;
    int hw = m - n * 3136;
    int h = hw / 56;
    an_[q] = n; ah_[q] = h; aw_[q] = hw - h * 56;
  }

  auto stageA2 = [&](unsigned char* bufA, int r, int s, int q0) {
#pragma unroll
    for (int q = q0; q < q0 + 2; ++q) {
      int hi = ah_[q] + r - 1;
      int wi = aw_[q] + s - 1;
      bool ok = ((unsigned)hi < 56u) && ((unsigned)wi < 56u);
      const unsigned char* src =
          ok ? act + (((an_[q] * 56 + hi) * 56 + wi) << 7) + schunk : zp + schunk;
      g2l16(src, bufA + ((srow + 64 * q) << 7) + sphys);
    }
  };
  auto stageB2 = [&](unsigned char* bufB, int rs) {
    const unsigned char* wseg = wt + rs * (KOUT * CIN);
#pragma unroll
    for (int q = 0; q < 2; ++q) {
      int kl = srow + 64 * q;
      g2l16(wseg + ((bn + kl) << 7) + schunk, bufB + (kl << 7) + sphys);
    }
  };

  const f32x4 zero = {0.f, 0.f, 0.f, 0.f};
  f32x4 acc[4][4];
#pragma unroll
  for (int i = 0; i < 4; ++i)
#pragma unroll
    for (int j = 0; j < 4; ++j) acc[i][j] = zero;

  // prologue: stage rs=0 into buffer 0, drain, barrier
  stageA2(ldsA[0], 0, 0, 0);
  stageA2(ldsA[0], 0, 0, 2);
  stageB2(ldsB[0], 0);
  __builtin_amdgcn_sched_barrier(0);
  asm volatile("s_waitcnt vmcnt(0)" ::: "memory");
  __builtin_amdgcn_s_barrier();

  const int xa = (lane & 7) << 4;              // read-side swizzle
  for (int t = 0; t < 9; ++t) {
    const int rn = (t + 1) / 3, sn = (t + 1) - 3 * rn;
    const unsigned char* bA = ldsA[t & 1];
    const unsigned char* bB = ldsB[t & 1];
    unsigned char* nA = ldsA[(t + 1) & 1];
    unsigned char* nB = ldsB[(t + 1) & 1];

#pragma unroll
    for (int P = 0; P < 4; ++P) {
      // ---- ds_read fragments for kk = P ----
      const int kb = (P << 5) + ((lane >> 4) << 3);
      long av[4], bv[4];
#pragma unroll
      for (int mi = 0; mi < 4; ++mi) {
        int row = (wr << 6) + (mi << 4) + (lane & 15);
        av[mi] = *(const long*)(bA + (row << 7) + (kb ^ xa));
      }
#pragma unroll
      for (int ni = 0; ni < 4; ++ni) {
        int col = (wc << 6) + (ni << 4) + (lane & 15);
        bv[ni] = *(const long*)(bB + (col << 7) + (kb ^ xa));
      }
      // ---- issue part of stage(t+1) ----
      if (t < 8) {
        if (P == 0)      stageA2(nA, rn, sn, 0);
        else if (P == 1) stageA2(nA, rn, sn, 2);
        else if (P == 2) stageB2(nB, t + 1);
      }
      __builtin_amdgcn_sched_barrier(0);
      __builtin_amdgcn_s_barrier();
      asm volatile("s_waitcnt lgkmcnt(0)" ::: "memory");
      __builtin_amdgcn_sched_barrier(0);
      __builtin_amdgcn_s_setprio(1);
#pragma unroll
      for (int mi = 0; mi < 4; ++mi)
#pragma unroll
        for (int ni = 0; ni < 4; ++ni)
          acc[mi][ni] = __builtin_amdgcn_mfma_f32_16x16x32_fp8_fp8(
              av[mi], bv[ni], acc[mi][ni], 0, 0, 0);
      __builtin_amdgcn_s_setprio(0);
      if (P == 3) {
        // all stage(t+1) loads (issued at P=0..2) must land before any wave
        // reads buffer t+1: per-thread drain, then workgroup barrier.
        __builtin_amdgcn_sched_barrier(0);
        asm volatile("s_waitcnt vmcnt(0)" ::: "memory");
      }
      __builtin_amdgcn_s_barrier();
    }
  }

  // epilogue: out[n][k][hw] = 4*acc + bias[k]; 4 consecutive m per lane = f32x4
#pragma unroll
  for (int ni = 0; ni < 4; ++ni) {
    int k = bn + (wc << 6) + (ni << 4) + (lane & 15);
    float bvv = bias[k];
#pragma unroll
    for (int mi = 0; mi < 4; ++mi) {
      int m = bm + (wr << 6) + (mi << 4) + ((lane >> 4) << 2);
      int n = m / 3136;
      int hw = m - n * 3136;
      f32x4 v = acc[mi][ni];
      v = v * 4.0f + bvv;
      *(f32x4*)(out + (size_t)(n * KOUT + k) * 3136 + hw) = v;
    }
  }
}

// ---------------------------------------------------------------------------
extern "C" void kernel_launch(void* const* d_in, const int* in_sizes, int n_in,
                              void* d_out, int out_size, void* d_ws, size_t ws_size,
                              hipStream_t stream) {
  const float* X = (const float*)d_in[0];
  const float* W = (const float*)d_in[1];
  const float* B = (const float*)d_in[2];
  float* out = (float*)d_out;

  unsigned char* act = (unsigned char*)d_ws;
  unsigned char* wtb = act + WT_OFF;
  unsigned char* zp  = act + ZP_OFF;

  hipLaunchKernelGGL(qdq_pack,    dim3(NB * HW), dim3(256), 0, stream, X, act);
  hipLaunchKernelGGL(pack_weight, dim3(288),     dim3(256), 0, stream, W, wtb,
                     (unsigned int*)zp);
  hipLaunchKernelGGL(conv_mfma,   dim3(392, 2),  dim3(512), 0, stream, act, wtb, zp, B,
                     out);
}

// Round 9
// 89.748 us; speedup vs baseline: 1.7601x; 1.2051x over previous
//
#include <hip/hip_runtime.h>
#include <cstdint>

// ---------------------------------------------------------------------------
// FP8 QDQ Conv2d:  out = conv2d(qdq_fp8(x,2), w*2, pad=1) + bias
//                = 4 * conv2d(fp8(x/2), fp8(w)) + bias     (exact in fp8)
// x: (32,128,56,56) f32 NCHW; w: (256,128,3,3) f32 (fp8-representable); b: (256,)
// out: (32,256,56,56) f32.  Implicit GEMM: M = 100352, N = 256, K = 9*128.
//
// R9 = R1's exact geometry (128x128 tile, 256 thr, 2x2 waves, 16x16x32 fp8
// MFMA, zero-page halo, same LDS layout/swizzle) upgraded to the T3-minimum
// 2-phase schedule (guide §5.5 T3 recipe, m248v2-verified):
//   prologue: STAGE(buf0, rs=0); barrier;
//   loop rs:  STAGE(buf[rs+1], rs+1); ds_read from buf[rs]; MFMA;
//             ONE vmcnt(0)+barrier    (compiler emits it at __syncthreads)
// The drain now waits on loads issued BEFORE a full ds_read+MFMA phase
// (~800 cyc cover) instead of R1's just-issued loads. LDS 64KB -> 2 blk/CU.
// ---------------------------------------------------------------------------

#define NB   32
#define CIN  128
#define HW   56
#define KOUT 256
#define MTOT (32 * 56 * 56)                      // 100352

#define ACT_BYTES (32u * 56u * 56u * 128u)       // 12,845,056  NHWC fp8
#define WT_OFF    ACT_BYTES
#define WT_BYTES  (9u * 256u * 128u)             // 294,912     [rs][k][c] fp8
#define ZP_OFF    (WT_OFF + WT_BYTES)            // 128B zero page for halo rows

typedef float        f32x4 __attribute__((ext_vector_type(4)));
typedef unsigned int u32x4 __attribute__((ext_vector_type(4)));

// --------------------------- fp8 pack helpers ------------------------------
__device__ __forceinline__ unsigned int pack2_fp8(float a, float b) {
  a = fminf(fmaxf(a, -448.f), 448.f);
  b = fminf(fmaxf(b, -448.f), 448.f);
  // v_cvt_pk_fp8_f32: RNE, saturating, OCP e4m3fn on gfx950. byte0=a, byte1=b.
  return (unsigned int)__builtin_amdgcn_cvt_pk_fp8_f32(a, b, 0, false);
}

// ------------------- kernel 1: qdq + NCHW -> NHWC fp8 ----------------------
__global__ __launch_bounds__(256) void qdq_pack(const float* __restrict__ X,
                                                unsigned char* __restrict__ act) {
  const int nh = blockIdx.x;               // 0..1791
  const int n = nh / HW, h = nh - n * HW;
  const float* xb = X + (size_t)n * (CIN * HW * HW) + h * HW;  // + c*3136 + w
  unsigned char* ob = act + (size_t)nh * (HW * CIN);

  for (int i = 0; i < 2; ++i) {
    int item = threadIdx.x + i * 256;
    if (item >= HW * 8) break;             // 56 w * 8 c-groups of 16
    int w = item % HW, cg = item / HW;
    unsigned int dw[4];
#pragma unroll
    for (int jj = 0; jj < 4; ++jj) {
      int c0 = cg * 16 + jj * 4;
      float v0 = xb[(c0 + 0) * 3136 + w] * 0.5f;
      float v1 = xb[(c0 + 1) * 3136 + w] * 0.5f;
      float v2 = xb[(c0 + 2) * 3136 + w] * 0.5f;
      float v3 = xb[(c0 + 3) * 3136 + w] * 0.5f;
      unsigned int lo = pack2_fp8(v0, v1) & 0xffffu;
      unsigned int hi = pack2_fp8(v2, v3) & 0xffffu;
      dw[jj] = lo | (hi << 16);
    }
    u32x4 v = {dw[0], dw[1], dw[2], dw[3]};
    *(u32x4*)(ob + w * CIN + cg * 16) = v;
  }
}

// --------------- kernel 2: weight OIHW f32 -> [rs][k][c] fp8 ---------------
__global__ __launch_bounds__(256) void pack_weight(const float* __restrict__ W,
                                                   unsigned char* __restrict__ wt,
                                                   unsigned int* __restrict__ zp) {
  if (blockIdx.x == 0 && threadIdx.x < 32) zp[threadIdx.x] = 0u;
  int gid = blockIdx.x * 256 + threadIdx.x;   // one dword (4 c) per thread
  int o = gid * 4;
  if (o >= (int)WT_BYTES) return;
  int rs = o >> 15;                // /32768 (= 256*128)
  int rem = o & 32767;
  int k  = rem >> 7;
  int c0 = rem & 127;
  // W[k][c][r][s] at k*1152 + c*9 + rs
  float v0 = W[k * 1152 + (c0 + 0) * 9 + rs];
  float v1 = W[k * 1152 + (c0 + 1) * 9 + rs];
  float v2 = W[k * 1152 + (c0 + 2) * 9 + rs];
  float v3 = W[k * 1152 + (c0 + 3) * 9 + rs];
  unsigned int dw = (pack2_fp8(v0, v1) & 0xffffu) | (pack2_fp8(v2, v3) << 16);
  *(unsigned int*)(wt + o) = dw;
}

// ------------------------- kernel 3: implicit GEMM -------------------------
__device__ __forceinline__ void g2l16(const void* g, void* l) {
  __builtin_amdgcn_global_load_lds((const __attribute__((address_space(1))) void*)g,
                                   (__attribute__((address_space(3))) void*)l,
                                   16, 0, 0);
}

__global__ __launch_bounds__(256) void conv_mfma(const unsigned char* __restrict__ act,
                                                 const unsigned char* __restrict__ wt,
                                                 const unsigned char* __restrict__ zp,
                                                 const float* __restrict__ bias,
                                                 float* __restrict__ out) {
  __shared__ __align__(16) unsigned char ldsA[2][16384];  // [128 m][128 c] x2
  __shared__ __align__(16) unsigned char ldsB[2][16384];  // [128 k][128 c] x2
  const int tid  = threadIdx.x;
  const int lane = tid & 63;
  const int wid  = tid >> 6;
  const int wr   = wid >> 1, wc = wid & 1;            // 2x2 waves -> 64x64 each
  const int bm   = blockIdx.x << 7;                   // 784 m-tiles
  const int bn   = blockIdx.y << 7;                   // 2 k-tiles

  // staging geometry: 8 threads x 16B per 128B row; 32 rows/round, 4 rounds
  const int srow   = tid >> 3;                        // 0..31
  const int sphys  = (tid & 7) << 4;                  // linear LDS dest chunk
  const int schunk = ((tid & 7) ^ (srow & 7)) << 4;   // XOR-swizzled global src chunk

  int an_[4], ah_[4], aw_[4];
#pragma unroll
  for (int q = 0; q < 4; ++q) {
    int m = bm + srow + 32 * q;
    int n = m / 3136;
    int hw = m - n * 3136;
    int h = hw / 56;
    an_[q] = n; ah_[q] = h; aw_[q] = hw - h * 56;
  }

  // stage one full rs-tile (A 128x128B + B 128x128B) into buffer `b`
  auto stage = [&](int b, int rs) {
    const int r = rs / 3, s = rs - 3 * r;
    const unsigned char* wseg = wt + rs * (KOUT * CIN);
#pragma unroll
    for (int q = 0; q < 4; ++q) {
      int hi = ah_[q] + r - 1;
      int wi = aw_[q] + s - 1;
      bool ok = ((unsigned)hi < 56u) && ((unsigned)wi < 56u);
      const unsigned char* src =
          ok ? act + (((an_[q] * 56 + hi) * 56 + wi) << 7) + schunk : zp + schunk;
      g2l16(src, &ldsA[b][((srow + 32 * q) << 7) + sphys]);
    }
#pragma unroll
    for (int q = 0; q < 4; ++q) {
      int kl = srow + 32 * q;
      g2l16(wseg + ((bn + kl) << 7) + schunk, &ldsB[b][(kl << 7) + sphys]);
    }
  };

  const f32x4 zero = {0.f, 0.f, 0.f, 0.f};
  f32x4 acc[4][4];
#pragma unroll
  for (int i = 0; i < 4; ++i)
#pragma unroll
    for (int j = 0; j < 4; ++j) acc[i][j] = zero;

  // prologue: stage rs=0 into buffer 0; single drain+barrier
  stage(0, 0);
  __syncthreads();

  const int kgrp = (lane >> 4) << 3;       // 8 k-bytes per lane-group
  const int xa   = (lane & 7) << 4;        // read-side swizzle (row&7 == lane&7)

  for (int rs = 0; rs < 9; ++rs) {
    // phase A: issue next tile's staging FIRST (cover = ds_reads + MFMA below)
    if (rs < 8) stage((rs + 1) & 1, rs + 1);

    // phase B: compute current tile from buf[rs&1]
    const unsigned char* bufA = ldsA[rs & 1];
    const unsigned char* bufB = ldsB[rs & 1];
#pragma unroll
    for (int kk = 0; kk < 4; ++kk) {
      const int kb = kk * 32 + kgrp;
      long av[4], bv[4];
#pragma unroll
      for (int mi = 0; mi < 4; ++mi) {
        int row = (wr << 6) + (mi << 4) + (lane & 15);
        av[mi] = *(const long*)(bufA + (row << 7) + (kb ^ xa));
      }
#pragma unroll
      for (int ni = 0; ni < 4; ++ni) {
        int col = (wc << 6) + (ni << 4) + (lane & 15);
        bv[ni] = *(const long*)(bufB + (col << 7) + (kb ^ xa));
      }
#pragma unroll
      for (int mi = 0; mi < 4; ++mi)
#pragma unroll
        for (int ni = 0; ni < 4; ++ni)
          acc[mi][ni] = __builtin_amdgcn_mfma_f32_16x16x32_fp8_fp8(
              av[mi], bv[ni], acc[mi][ni], 0, 0, 0);
    }

    // ONE drain+barrier per step (compiler emits s_waitcnt vmcnt(0) lgkmcnt(0)
    // before s_barrier). Ensures stage(rs+1) landed and all reads of the
    // buffer being overwritten next step are done.
    __syncthreads();
  }

  // epilogue: out[n][k][hw] = 4*acc + bias[k]; 4 consecutive m per lane = float4
#pragma unroll
  for (int ni = 0; ni < 4; ++ni) {
    int k = bn + (wc << 6) + (ni << 4) + (lane & 15);
    float bvv = bias[k];
#pragma unroll
    for (int mi = 0; mi < 4; ++mi) {
      int m = bm + (wr << 6) + (mi << 4) + ((lane >> 4) << 2);
      int n = m / 3136;
      int hw = m - n * 3136;
      f32x4 v = acc[mi][ni];
      v = v * 4.0f + bvv;
      *(f32x4*)(out + (size_t)(n * KOUT + k) * 3136 + hw) = v;
    }
  }
}

// ---------------------------------------------------------------------------
extern "C" void kernel_launch(void* const* d_in, const int* in_sizes, int n_in,
                              void* d_out, int out_size, void* d_ws, size_t ws_size,
                              hipStream_t stream) {
  const float* X = (const float*)d_in[0];
  const float* W = (const float*)d_in[1];
  const float* B = (const float*)d_in[2];
  float* out = (float*)d_out;

  unsigned char* act = (unsigned char*)d_ws;
  unsigned char* wtb = act + WT_OFF;
  unsigned char* zp  = act + ZP_OFF;

  hipLaunchKernelGGL(qdq_pack,    dim3(NB * HW), dim3(256), 0, stream, X, act);
  hipLaunchKernelGGL(pack_weight, dim3(288),     dim3(256), 0, stream, W, wtb,
                     (unsigned int*)zp);
  hipLaunchKernelGGL(conv_mfma,   dim3(784, 2),  dim3(256), 0, stream, act, wtb, zp, B,
                     out);
}